// Round 19
// baseline (546.709 us; speedup 1.0000x reference)
//
#include <hip/hip_runtime.h>
#include <hip/hip_bf16.h>

typedef __bf16 bf16;
typedef __bf16 bf16x8 __attribute__((ext_vector_type(8)));
typedef float f32x4 __attribute__((ext_vector_type(4)));

#define DEVINL __device__ __forceinline__

constexpr int L_ = 2, R_ = 4, S_ = 1024, H_ = 1024;
constexpr int NH_ = 16, NKV_ = 8, DH_ = 128;
constexpr int FF_ = 3072;
constexpr int T_ = R_ * S_;  // 4096 tokens

DEVINL void gload16(const bf16* g, bf16* l) {
    __builtin_amdgcn_global_load_lds(
        (const __attribute__((address_space(1))) void*)g,
        (__attribute__((address_space(3))) void*)l, 16, 0, 0);
}

// ---------------------------------------------------------------- RoPE tables
__global__ void rope_tables_kernel(float* __restrict__ cosb, float* __restrict__ sinb) {
    int s = blockIdx.x;
    int i = threadIdx.x;  // 0..63
    float inv = __expf(-(float)i * (1.0f / 64.0f) * 13.815510557964274f);  // 1e6^(-i/64)
    float f = (float)s * inv;
    cosb[s * 64 + i] = cosf(f);
    sinb[s * 64 + i] = sinf(f);
}

// ---------------------------------------------------------------- RMSNorm (f32x4 loads)
template <bool OUT_BF16>
__global__ __launch_bounds__(256) void rmsnorm_kernel(const float* __restrict__ x,
                                                      const float* __restrict__ w,
                                                      void* __restrict__ out) {
    int row = blockIdx.x;
    const float* xr = x + (size_t)row * H_;
    int t = threadIdx.x;
    f32x4 v = *(const f32x4*)(xr + t * 4);
    float ss = v[0] * v[0] + v[1] * v[1] + v[2] * v[2] + v[3] * v[3];
#pragma unroll
    for (int off = 32; off; off >>= 1) ss += __shfl_xor(ss, off);
    __shared__ float part[4];
    if ((t & 63) == 0) part[t >> 6] = ss;
    __syncthreads();
    ss = part[0] + part[1] + part[2] + part[3];
    float r = rsqrtf(ss * (1.0f / (float)H_) + 1e-6f);
    f32x4 wv = *(const f32x4*)(w + t * 4);
#pragma unroll
    for (int j = 0; j < 4; ++j) {
        float o = v[j] * r * wv[j];
        if constexpr (OUT_BF16)
            ((bf16*)out)[(size_t)row * H_ + t * 4 + j] = (bf16)o;
        else
            ((float*)out)[(size_t)row * H_ + t * 4 + j] = o;
    }
}

// ---------------------------------------------------------------- merged weight transpose (all 7 per layer, 1 dispatch)
__global__ __launch_bounds__(256) void transpose_all_kernel(
    const float* __restrict__ Wq, const float* __restrict__ Wk, const float* __restrict__ Wv,
    const float* __restrict__ Wo, const float* __restrict__ Wg, const float* __restrict__ Wu,
    const float* __restrict__ Wd, bf16* __restrict__ wqkv_t, bf16* __restrict__ wo_t,
    bf16* __restrict__ wgu_t, bf16* __restrict__ wd_t) {
    __shared__ float tile[32][33];
    int bid = blockIdx.x;
    const float* in;
    bf16* out;
    int Rk, Cn, mode, tid;
    if (bid < 2048) { in = Wq; out = wqkv_t; Rk = 1024; Cn = 2048; mode = 0; tid = bid; }
    else if (bid < 3072) { in = Wk; out = wqkv_t + (size_t)2048 * 1024; Rk = 1024; Cn = 1024; mode = 0; tid = bid - 2048; }
    else if (bid < 4096) { in = Wv; out = wqkv_t + (size_t)3072 * 1024; Rk = 1024; Cn = 1024; mode = 0; tid = bid - 3072; }
    else if (bid < 6144) { in = Wo; out = wo_t; Rk = 2048; Cn = 1024; mode = 0; tid = bid - 4096; }
    else if (bid < 9216) { in = Wg; out = wgu_t; Rk = 1024; Cn = 3072; mode = 1; tid = bid - 6144; }
    else if (bid < 12288) { in = Wu; out = wgu_t; Rk = 1024; Cn = 3072; mode = 2; tid = bid - 9216; }
    else { in = Wd; out = wd_t; Rk = 3072; Cn = 1024; mode = 0; tid = bid - 12288; }
    int nbx = Cn >> 5;
    int c0 = (tid % nbx) * 32, r0 = (tid / nbx) * 32;
    int t = threadIdx.x;
    int tc = t & 31, tr = t >> 5;
#pragma unroll
    for (int i = 0; i < 4; ++i) {
        int r = tr + i * 8;
        tile[r][tc] = in[(size_t)(r0 + r) * Cn + c0 + tc];
    }
    __syncthreads();
#pragma unroll
    for (int i = 0; i < 4; ++i) {
        int c = c0 + tr + i * 8;
        int n = (mode == 0) ? c : (((c >> 4) << 5) + ((mode == 2) ? 16 : 0) + (c & 15));
        out[(size_t)n * Rk + r0 + tc] = (bf16)tile[tc][tr + i * 8];
    }
}

// ---------------------------------------------------------------- V transpose: qkv[r*S+s][3072+c] -> vt[(r*1024+c)][s]
__global__ __launch_bounds__(256) void vt_kernel(const bf16* __restrict__ qkv,
                                                 bf16* __restrict__ vt) {
    __shared__ bf16 tile[32][34];
    int s0 = blockIdx.x * 32, c0 = blockIdx.y * 32, r = blockIdx.z;
    int t = threadIdx.x, tc = t & 31, tr = t >> 5;
#pragma unroll
    for (int i = 0; i < 4; ++i) {
        int s = tr + i * 8;
        tile[s][tc] = qkv[(size_t)(r * 1024 + s0 + s) * 4096 + 3072 + c0 + tc];
    }
    __syncthreads();
#pragma unroll
    for (int i = 0; i < 4; ++i) {
        int c = tr + i * 8;
        vt[((size_t)(r * 1024 + c0 + c)) * 1024 + s0 + tc] = tile[tc][c];
    }
}

// ---------------------------------------------------------------- gemmT: 256x256 tile, 8 waves (2M x 4N) of 128x64, BK=32
// 3-buffer ring 96KB (1 block/CU), counted vmcnt(4), bn-fastest XCD slice map.
template <int EPI>
__global__ __launch_bounds__(512, 2) void gemmT_kernel(const bf16* __restrict__ A,
                                                       const bf16* __restrict__ Bt,
                                                       void* __restrict__ out,
                                                       int M, int N, int K) {
    __shared__ bf16 lds[49152];  // A: 3 x 8192 elems [0,24576); B: 3 x 8192 [24576,49152)
    const int NT = K >> 5;
    int nbm = M >> 8, nbn = N >> 8;
    int slice = nbn >> 3;
    int id = blockIdx.x;
    int xcd = id & 7, wi = id >> 3;
    int bm = (wi / slice) << 8;
    int bn = (xcd * slice + wi % slice) << 8;
    int t = threadIdx.x, lane = t & 63, w = t >> 6;
    int wm = w >> 2, wn = w & 3;
    int hi = lane >> 4, f = lane & 15;

    int r0 = t >> 2;
    int so = (((t & 3) ^ ((r0 >> 1) & 3)) << 3);
    const bf16* aS0 = A + (size_t)(bm + r0) * K + so;
    const bf16* aS1 = A + (size_t)(bm + 128 + r0) * K + so;
    const bf16* bS0 = Bt + (size_t)(bn + r0) * K + so;
    const bf16* bS1 = Bt + (size_t)(bn + 128 + r0) * K + so;

    f32x4 acc[8][4] = {};

    auto stage = [&](int tt, int sb) {
        gload16(aS0 + tt * 32, lds + sb * 8192 + w * 512);
        gload16(aS1 + tt * 32, lds + sb * 8192 + 4096 + w * 512);
        gload16(bS0 + tt * 32, lds + 24576 + sb * 8192 + w * 512);
        gload16(bS1 + tt * 32, lds + 24576 + sb * 8192 + 4096 + w * 512);
    };

    stage(0, 0);
    stage(1, 1);
    asm volatile("s_waitcnt vmcnt(4)" ::: "memory");
    __builtin_amdgcn_s_barrier();

    int cb = 0;
    for (int tau = 0; tau < NT; ++tau) {
        const bf16* aB = lds + cb * 8192;
        const bf16* bB = lds + 24576 + cb * 8192;
        if (tau + 2 < NT) stage(tau + 2, (cb == 0) ? 2 : cb - 1);
        bf16x8 af[8], bfv[4];
#pragma unroll
        for (int mf = 0; mf < 8; ++mf) {
            int row = wm * 128 + mf * 16 + f;
            af[mf] = *(const bf16x8*)(aB + row * 32 + ((hi ^ ((row >> 1) & 3)) << 3));
        }
#pragma unroll
        for (int nf = 0; nf < 4; ++nf) {
            int row = wn * 64 + nf * 16 + f;
            bfv[nf] = *(const bf16x8*)(bB + row * 32 + ((hi ^ ((row >> 1) & 3)) << 3));
        }
        __builtin_amdgcn_s_setprio(1);
#pragma unroll
        for (int mf = 0; mf < 8; ++mf)
#pragma unroll
            for (int nf = 0; nf < 4; ++nf)
                acc[mf][nf] = __builtin_amdgcn_mfma_f32_16x16x32_bf16(af[mf], bfv[nf],
                                                                      acc[mf][nf], 0, 0, 0);
        __builtin_amdgcn_s_setprio(0);
        if (tau < NT - 2)
            asm volatile("s_waitcnt vmcnt(4)" ::: "memory");
        else
            asm volatile("s_waitcnt vmcnt(0)" ::: "memory");
        __builtin_amdgcn_s_barrier();
        cb = (cb == 2) ? 0 : cb + 1;
    }

    int rb = bm + wm * 128 + hi * 4;
    int cb2 = bn + wn * 64 + f;
#pragma unroll
    for (int mf = 0; mf < 8; ++mf)
#pragma unroll
        for (int nf = 0; nf < 4; ++nf)
#pragma unroll
            for (int g = 0; g < 4; ++g)
                ((bf16*)out)[(size_t)(rb + mf * 16 + g) * N + cb2 + nf * 16] =
                    (bf16)acc[mf][nf][g];
}

// ---------------------------------------------------------------- gemmP: 128x256 tile, wave 64x64, BK=32
// 3-buffer ring 72KB (2 blocks/CU), counted vmcnt(3), bn-fastest XCD slice map.
// EPI: 5 = fused gate-up silu(even16)*odd16 -> bf16 [M][N/2]
template <int EPI>
__global__ __launch_bounds__(512, 4) void gemmP_kernel(const bf16* __restrict__ A,
                                                       const bf16* __restrict__ Bt,
                                                       void* __restrict__ out,
                                                       int M, int N, int K) {
    __shared__ bf16 lds[36864];  // A: 3 x 4096 elems [0,12288); B: 3 x 8192 [12288,36864)
    const int NT = K >> 5;
    int nbm = M >> 7, nbn = N >> 8;
    int slice = nbn >> 3;
    int id = blockIdx.x;
    int xcd = id & 7, wi = id >> 3;
    int bm = (wi / slice) << 7;
    int bn = (xcd * slice + wi % slice) << 8;
    int t = threadIdx.x, lane = t & 63, w = t >> 6;
    int wm = w >> 2, wn = w & 3;
    int hi = lane >> 4, f = lane & 15;

    int srow = t >> 2;
    int ssc = (t & 3) ^ ((srow >> 1) & 3);
    const bf16* aSrc = A + (size_t)(bm + srow) * K + (ssc << 3);
    const bf16* b0Src = Bt + (size_t)(bn + srow) * K + (ssc << 3);
    const bf16* b1Src = Bt + (size_t)(bn + 128 + srow) * K + (ssc << 3);

    f32x4 acc[4][4] = {};

    auto stage = [&](int tt, int sb) {
        gload16(aSrc + tt * 32, lds + sb * 4096 + w * 512);
        gload16(b0Src + tt * 32, lds + 12288 + sb * 8192 + w * 512);
        gload16(b1Src + tt * 32, lds + 12288 + sb * 8192 + 4096 + w * 512);
    };

    stage(0, 0);
    stage(1, 1);
    asm volatile("s_waitcnt vmcnt(3)" ::: "memory");
    __builtin_amdgcn_s_barrier();

    int cb = 0;
    for (int tau = 0; tau < NT; ++tau) {
        const bf16* aB = lds + cb * 4096;
        const bf16* bB = lds + 12288 + cb * 8192;
        if (tau + 2 < NT) stage(tau + 2, (cb == 0) ? 2 : cb - 1);
        bf16x8 af[4], bfv[4];
#pragma unroll
        for (int mf = 0; mf < 4; ++mf) {
            int row = wm * 64 + mf * 16 + f;
            af[mf] = *(const bf16x8*)(aB + row * 32 + ((hi ^ ((row >> 1) & 3)) << 3));
        }
#pragma unroll
        for (int nf = 0; nf < 4; ++nf) {
            int row = wn * 64 + nf * 16 + f;
            bfv[nf] = *(const bf16x8*)(bB + row * 32 + ((hi ^ ((row >> 1) & 3)) << 3));
        }
        __builtin_amdgcn_s_setprio(1);
#pragma unroll
        for (int mf = 0; mf < 4; ++mf)
#pragma unroll
            for (int nf = 0; nf < 4; ++nf)
                acc[mf][nf] = __builtin_amdgcn_mfma_f32_16x16x32_bf16(af[mf], bfv[nf],
                                                                      acc[mf][nf], 0, 0, 0);
        __builtin_amdgcn_s_setprio(0);
        if (tau < NT - 2)
            asm volatile("s_waitcnt vmcnt(3)" ::: "memory");
        else
            asm volatile("s_waitcnt vmcnt(0)" ::: "memory");
        __builtin_amdgcn_s_barrier();
        cb = (cb == 2) ? 0 : cb + 1;
    }

    int rb = bm + wm * 64 + hi * 4;
#pragma unroll
    for (int mf = 0; mf < 4; ++mf) {
        if constexpr (EPI == 5) {
#pragma unroll
            for (int p = 0; p < 2; ++p) {
                int col = ((bn + wn * 64) >> 1) + p * 16 + f;
#pragma unroll
                for (int g = 0; g < 4; ++g) {
                    float gv = acc[mf][2 * p][g], uv = acc[mf][2 * p + 1][g];
                    float sv = gv / (1.0f + __expf(-gv));
                    ((bf16*)out)[(size_t)(rb + mf * 16 + g) * (N / 2) + col] = (bf16)(sv * uv);
                }
            }
        } else {
            int cb2 = bn + wn * 64 + f;
#pragma unroll
            for (int nf = 0; nf < 4; ++nf)
#pragma unroll
                for (int g = 0; g < 4; ++g)
                    ((bf16*)out)[(size_t)(rb + mf * 16 + g) * N + cb2 + nf * 16] =
                        (bf16)acc[mf][nf][g];
        }
    }
}

// ---------------------------------------------------------------- gemmD: skinny-N GEMM, 128 threads / 2 waves of 64x64
// 64x128 tile, BK=32; per wave 8 ds_read_b128 per 16 MFMA (0.5 ratio, gemmP-class).
// 3-slot ring 36KB (4 blocks/CU = 8 waves/CU), counted vmcnt(6) (6 gloads/stage).
// XCD bn-slice map (each XCD owns one 128-col stripe). EPI 4: f32 out = acc + res.
template <int EPI>
__global__ __launch_bounds__(128, 2) void gemmD_kernel(const bf16* __restrict__ A,
                                                       const bf16* __restrict__ Bt,
                                                       void* __restrict__ out,
                                                       const float* __restrict__ res,
                                                       int M, int N, int K) {
    __shared__ bf16 lds[18432];  // 3 slots x 6144 elems (A 64x32 = 2048, B 128x32 = 4096)
    const int NT = K >> 5;
    int nbm = M >> 6;  // BM=64
    int id = blockIdx.x;
    int xcd = id & 7, wi = id >> 3;
    int bm = (wi % nbm) << 6, bn = xcd << 7;
    int t = threadIdx.x, lane = t & 63, w = t >> 6;  // 2 waves
    int hi = lane >> 4, f = lane & 15;

    // staging (128 threads, 6 x 16B chunks each): A rows r0, r0+32; B rows r0, +32, +64, +96.
    // chunk swizzle (t&3)^((r0>>1)&3) — invariant under r0 += 32.
    int r0 = t >> 2;
    int sw = ((t & 3) ^ ((r0 >> 1) & 3)) << 3;
    const bf16* aS0 = A + (size_t)(bm + r0) * K + sw;
    const bf16* aS1 = A + (size_t)(bm + 32 + r0) * K + sw;
    const bf16* bS0 = Bt + (size_t)(bn + r0) * K + sw;
    const bf16* bS1 = Bt + (size_t)(bn + 32 + r0) * K + sw;
    const bf16* bS2 = Bt + (size_t)(bn + 64 + r0) * K + sw;
    const bf16* bS3 = Bt + (size_t)(bn + 96 + r0) * K + sw;

    f32x4 acc[4][4] = {};

    auto stage = [&](int tt, int sb) {
        bf16* base = lds + sb * 6144;
        gload16(aS0 + tt * 32, base + w * 512);
        gload16(aS1 + tt * 32, base + 1024 + w * 512);
        gload16(bS0 + tt * 32, base + 2048 + w * 512);
        gload16(bS1 + tt * 32, base + 3072 + w * 512);
        gload16(bS2 + tt * 32, base + 4096 + w * 512);
        gload16(bS3 + tt * 32, base + 5120 + w * 512);
    };

    stage(0, 0);
    stage(1, 1);
    asm volatile("s_waitcnt vmcnt(6)" ::: "memory");
    __builtin_amdgcn_s_barrier();

    int cb = 0;
    for (int tau = 0; tau < NT; ++tau) {
        const bf16* aB = lds + cb * 6144;
        const bf16* bB = aB + 2048;
        if (tau + 2 < NT) stage(tau + 2, (cb == 0) ? 2 : cb - 1);
        bf16x8 af[4], bfv[4];
#pragma unroll
        for (int mf = 0; mf < 4; ++mf) {
            int row = mf * 16 + f;
            af[mf] = *(const bf16x8*)(aB + row * 32 + ((hi ^ ((row >> 1) & 3)) << 3));
        }
#pragma unroll
        for (int nf = 0; nf < 4; ++nf) {
            int row = w * 64 + nf * 16 + f;
            bfv[nf] = *(const bf16x8*)(bB + row * 32 + ((hi ^ ((row >> 1) & 3)) << 3));
        }
        __builtin_amdgcn_s_setprio(1);
#pragma unroll
        for (int mf = 0; mf < 4; ++mf)
#pragma unroll
            for (int nf = 0; nf < 4; ++nf)
                acc[mf][nf] = __builtin_amdgcn_mfma_f32_16x16x32_bf16(af[mf], bfv[nf],
                                                                      acc[mf][nf], 0, 0, 0);
        __builtin_amdgcn_s_setprio(0);
        if (tau < NT - 2)
            asm volatile("s_waitcnt vmcnt(6)" ::: "memory");  // counted: tile tau+1 complete
        else
            asm volatile("s_waitcnt vmcnt(0)" ::: "memory");  // drain
        __builtin_amdgcn_s_barrier();
        cb = (cb == 2) ? 0 : cb + 1;
    }

    int rb = bm + hi * 4;
    int cb2 = bn + w * 64 + f;
#pragma unroll
    for (int mf = 0; mf < 4; ++mf)
#pragma unroll
        for (int nf = 0; nf < 4; ++nf)
#pragma unroll
            for (int g = 0; g < 4; ++g) {
                size_t idx = (size_t)(rb + mf * 16 + g) * N + cb2 + nf * 16;
                ((float*)out)[idx] = acc[mf][nf][g] + res[idx];
            }
}

// ---------------------------------------------------------------- per-head RMS + RoPE for q/k
DEVINL void head_norm_rope(const bf16* __restrict__ src, const float* __restrict__ w,
                           const float* __restrict__ cosb, const float* __restrict__ sinb,
                           int s, int ln, bf16* __restrict__ dst) {
    float x0 = (float)src[ln], x1 = (float)src[ln + 32];
    float x2 = (float)src[ln + 64], x3 = (float)src[ln + 96];
    float ss = x0 * x0 + x1 * x1 + x2 * x2 + x3 * x3;
#pragma unroll
    for (int off = 16; off; off >>= 1) ss += __shfl_xor(ss, off);
    float rr = rsqrtf(ss * (1.0f / 128.0f) + 1e-6f);
    float n0 = x0 * rr * w[ln], n1 = x1 * rr * w[ln + 32];
    float n2 = x2 * rr * w[ln + 64], n3 = x3 * rr * w[ln + 96];
    float c0 = cosb[s * 64 + ln], c1 = cosb[s * 64 + ln + 32];
    float s0 = sinb[s * 64 + ln], s1 = sinb[s * 64 + ln + 32];
    dst[ln] = (bf16)(n0 * c0 - n2 * s0);
    dst[ln + 32] = (bf16)(n1 * c1 - n3 * s1);
    dst[ln + 64] = (bf16)(n2 * c0 + n0 * s0);
    dst[ln + 96] = (bf16)(n3 * c1 + n1 * s1);
}

__global__ __launch_bounds__(256) void qkv_post_kernel(const bf16* __restrict__ qkv,
                                                       const float* __restrict__ qw,
                                                       const float* __restrict__ kw,
                                                       const float* __restrict__ cosb,
                                                       const float* __restrict__ sinb,
                                                       bf16* __restrict__ qo,
                                                       bf16* __restrict__ ko) {
    int tok = blockIdx.x;
    int r = tok >> 10, s = tok & 1023;
    int t = threadIdx.x;
    int g = t >> 5;  // 0..7
    int ln = t & 31;
    const bf16* row = qkv + (size_t)tok * 4096;
#pragma unroll
    for (int hh = 0; hh < 2; ++hh) {
        int h = g + hh * 8;
        head_norm_rope(row + h * 128, qw, cosb, sinb, s, ln,
                       qo + ((size_t)(r * NH_ + h) * S_ + s) * 128);
    }
    head_norm_rope(row + 2048 + g * 128, kw, cosb, sinb, s, ln,
                   ko + ((size_t)(r * NKV_ + g) * S_ + s) * 128);
}

// ---------------------------------------------------------------- flash attention (causal, GQA), NO-MAX softmax
// |q|=|k|=sqrt(128) after unit-weight RMS (RoPE preserves norm) -> |s*scale| <= 11.32, exp safe.
// Row-sum on MFMA pipe via ones operand; zero cross-lane ops; Pl XOR-swizzled.
__global__ __launch_bounds__(256, 2) void flash_kernel(const bf16* __restrict__ q,
                                                       const bf16* __restrict__ k,
                                                       const bf16* __restrict__ vt,
                                                       bf16* __restrict__ out) {
    __shared__ bf16 Kl[64 * 128];    // [kv][d], swizzled
    __shared__ bf16 Vl[128 * 64];    // [d][kv], swizzled
    __shared__ bf16 Pl[4][32 * 64];  // per-wave P, XOR-swizzled
    int bid = blockIdx.x;
    int grp = bid & 63, slot = bid >> 6;
    int strip = (slot < 4) ? (7 - slot) : (slot - 4);  // pair heavy+light per CU
    int h = 2 * (grp & 7) + ((grp >> 3) & 1);
    int r = grp >> 4;
    int kvh = h >> 1;

    int t = threadIdx.x, lane = t & 63, w = t >> 6;
    int arow = lane & 15, hi = lane >> 4;
    int a7 = arow & 7;
    int grow = hi * 4;
    int qbase = strip * 128 + w * 32;

    const bf16* qp = q + ((size_t)(r * NH_ + h) * S_ + qbase) * 128;
    bf16x8 qf[2][4];
#pragma unroll
    for (int m = 0; m < 2; ++m)
#pragma unroll
        for (int kc = 0; kc < 4; ++kc)
            qf[m][kc] = *(const bf16x8*)(qp + (size_t)(m * 16 + arow) * 128 + kc * 32 + hi * 8);

    const bf16* kp = k + (size_t)(r * NKV_ + kvh) * S_ * 128;
    const bf16* vp = vt + (size_t)(r * NKV_ + kvh) * 128 * S_;

    int krow0 = t >> 4, kc16 = t & 15;
    int vrow0 = t >> 3, vc16 = t & 7;

    bf16x8 ones;
#pragma unroll
    for (int i = 0; i < 8; ++i) ones[i] = (bf16)1.0f;

    f32x4 ao[2][8] = {};
    f32x4 aol[2] = {};
    const float scale = 0.08838834764831845f;

    int nt = 2 * (strip + 1);
    bf16x8 krs[4], vrs[4];
#pragma unroll
    for (int i = 0; i < 4; ++i)
        krs[i] = *(const bf16x8*)(kp + (size_t)(krow0 + 16 * i) * 128 + kc16 * 8);
#pragma unroll
    for (int i = 0; i < 4; ++i)
        vrs[i] = *(const bf16x8*)(vp + (size_t)(vrow0 + 32 * i) * S_ + vc16 * 8);

    for (int it = 0; it < nt; ++it) {
        int kv0 = it * 64;
        __syncthreads();
#pragma unroll
        for (int i = 0; i < 4; ++i) {
            int row = krow0 + 16 * i;
            *(bf16x8*)(&Kl[row * 128 + ((kc16 ^ (row & 7)) * 8)]) = krs[i];
        }
#pragma unroll
        for (int i = 0; i < 4; ++i) {
            int row = vrow0 + 32 * i;
            *(bf16x8*)(&Vl[row * 64 + ((vc16 ^ (row & 7)) * 8)]) = vrs[i];
        }
        __syncthreads();
        if (it + 1 < nt) {
            int kvn = kv0 + 64;
#pragma unroll
            for (int i = 0; i < 4; ++i)
                krs[i] = *(const bf16x8*)(kp + (size_t)(kvn + krow0 + 16 * i) * 128 + kc16 * 8);
#pragma unroll
            for (int i = 0; i < 4; ++i)
                vrs[i] = *(const bf16x8*)(vp + (size_t)(vrow0 + 32 * i) * S_ + kvn + vc16 * 8);
        }
        f32x4 sc[2][4];
#pragma unroll
        for (int m = 0; m < 2; ++m)
#pragma unroll
            for (int n = 0; n < 4; ++n) sc[m][n] = (f32x4){0.f, 0.f, 0.f, 0.f};
#pragma unroll
        for (int n = 0; n < 4; ++n) {
            int krw = n * 16 + arow;
#pragma unroll
            for (int kc = 0; kc < 4; ++kc) {
                bf16x8 kf = *(const bf16x8*)(&Kl[krw * 128 + (((kc * 4 + hi) ^ a7) * 8)]);
                sc[0][n] = __builtin_amdgcn_mfma_f32_16x16x32_bf16(qf[0][kc], kf, sc[0][n], 0, 0, 0);
                sc[1][n] = __builtin_amdgcn_mfma_f32_16x16x32_bf16(qf[1][kc], kf, sc[1][n], 0, 0, 0);
            }
        }
#pragma unroll
        for (int m = 0; m < 2; ++m) {
            bool msk = (kv0 + 64 > qbase + m * 16);
#pragma unroll
            for (int n = 0; n < 4; ++n) {
                int chnk = 2 * n + (arow >> 3);
#pragma unroll
                for (int g = 0; g < 4; ++g) {
                    float sval = sc[m][n][g] * scale;
                    if (msk && (kv0 + n * 16 + arow > qbase + m * 16 + grow + g)) sval = -1e30f;
                    float p = __expf(sval);
                    int qr = m * 16 + grow + g;
                    Pl[w][qr * 64 + ((chnk ^ (qr & 7)) * 8) + a7] = (bf16)p;
                }
            }
        }
        bf16x8 pf[2][2];
#pragma unroll
        for (int m = 0; m < 2; ++m) {
            int qr = m * 16 + arow;
#pragma unroll
            for (int ks = 0; ks < 2; ++ks)
                pf[m][ks] = *(const bf16x8*)(&Pl[w][qr * 64 + (((ks * 4 + hi) ^ a7) * 8)]);
        }
#pragma unroll
        for (int m = 0; m < 2; ++m) {
            aol[m] = __builtin_amdgcn_mfma_f32_16x16x32_bf16(pf[m][0], ones, aol[m], 0, 0, 0);
            aol[m] = __builtin_amdgcn_mfma_f32_16x16x32_bf16(pf[m][1], ones, aol[m], 0, 0, 0);
        }
#pragma unroll
        for (int c = 0; c < 8; ++c) {
            int vrw = c * 16 + arow;
#pragma unroll
            for (int ks = 0; ks < 2; ++ks) {
                bf16x8 vf = *(const bf16x8*)(&Vl[vrw * 64 + (((ks * 4 + hi) ^ a7) * 8)]);
                ao[0][c] = __builtin_amdgcn_mfma_f32_16x16x32_bf16(pf[0][ks], vf, ao[0][c], 0, 0, 0);
                ao[1][c] = __builtin_amdgcn_mfma_f32_16x16x32_bf16(pf[1][ks], vf, ao[1][c], 0, 0, 0);
            }
        }
    }
#pragma unroll
    for (int m = 0; m < 2; ++m) {
        f32x4 rl;
#pragma unroll
        for (int g = 0; g < 4; ++g) rl[g] = 1.0f / aol[m][g];
#pragma unroll
        for (int c = 0; c < 8; ++c)
#pragma unroll
            for (int g = 0; g < 4; ++g) {
                int rq = qbase + m * 16 + grow + g;
                out[(size_t)(r * S_ + rq) * 2048 + h * 128 + c * 16 + arow] =
                    (bf16)(ao[m][c][g] * rl[g]);
            }
    }
}

// ---------------------------------------------------------------- host
extern "C" void kernel_launch(void* const* d_in, const int* in_sizes, int n_in,
                              void* d_out, int out_size, void* d_ws, size_t ws_size,
                              hipStream_t stream) {
    const float* hidden = (const float*)d_in[0];
    const float* Wq = (const float*)d_in[1];
    const float* Wk = (const float*)d_in[2];
    const float* Wv = (const float*)d_in[3];
    const float* Wo = (const float*)d_in[4];
    const float* qnw = (const float*)d_in[5];
    const float* knw = (const float*)d_in[6];
    const float* ln1 = (const float*)d_in[7];
    const float* ln2 = (const float*)d_in[8];
    const float* Wg = (const float*)d_in[9];
    const float* Wu = (const float*)d_in[10];
    const float* Wd = (const float*)d_in[11];
    const float* fnw = (const float*)d_in[12];
    float* out = (float*)d_out;

    char* ws = (char*)d_ws;
    size_t off = 0;
    auto alloc = [&](size_t bytes) -> char* {
        char* p = ws + off;
        off += (bytes + 255) & ~(size_t)255;
        return p;
    };
    float* cosb = (float*)alloc((size_t)S_ * 64 * 4);
    float* sinb = (float*)alloc((size_t)S_ * 64 * 4);
    float* x_ws = (float*)alloc((size_t)T_ * H_ * 4);
    bf16* hbuf = (bf16*)alloc((size_t)T_ * H_ * 2);
    bf16* qkv = (bf16*)alloc((size_t)T_ * 4096 * 2);  // shared region: qkv then act
    bf16* act = qkv;
    bf16* qb = (bf16*)alloc((size_t)R_ * NH_ * S_ * 128 * 2);
    bf16* kb = (bf16*)alloc((size_t)R_ * NKV_ * S_ * 128 * 2);
    bf16* vtb = (bf16*)alloc((size_t)R_ * NKV_ * 128 * S_ * 2);
    bf16* attn = (bf16*)alloc((size_t)T_ * 2048 * 2);
    bf16* wqkv_t = (bf16*)alloc((size_t)4096 * 1024 * 2);
    bf16* wo_t = (bf16*)alloc((size_t)1024 * 2048 * 2);
    bf16* wgu_t = (bf16*)alloc((size_t)6144 * 1024 * 2);
    bf16* wd_t = (bf16*)alloc((size_t)1024 * 3072 * 2);

    rope_tables_kernel<<<S_, 64, 0, stream>>>(cosb, sinb);

    const float* xin = hidden;
    for (int l = 0; l < L_; ++l) {
        transpose_all_kernel<<<15360, 256, 0, stream>>>(
            Wq + (size_t)l * H_ * 2048, Wk + (size_t)l * H_ * 1024, Wv + (size_t)l * H_ * 1024,
            Wo + (size_t)l * 2048 * 1024, Wg + (size_t)l * H_ * 3072, Wu + (size_t)l * H_ * 3072,
            Wd + (size_t)l * 3072 * 1024, wqkv_t, wo_t, wgu_t, wd_t);

        // attention block
        rmsnorm_kernel<true><<<T_, 256, 0, stream>>>(xin, ln1 + (size_t)l * H_, hbuf);
        gemmT_kernel<1><<<256, 512, 0, stream>>>(hbuf, wqkv_t, qkv, 4096, 4096, 1024);
        qkv_post_kernel<<<T_, 256, 0, stream>>>(qkv, qnw + (size_t)l * 128, knw + (size_t)l * 128,
                                                cosb, sinb, qb, kb);
        vt_kernel<<<dim3(32, 32, 4), 256, 0, stream>>>(qkv, vtb);
        flash_kernel<<<512, 256, 0, stream>>>(qb, kb, vtb, attn);
        gemmD_kernel<4><<<512, 128, 0, stream>>>(attn, wo_t, x_ws, xin, 4096, 1024, 2048);
        // MLP block
        rmsnorm_kernel<true><<<T_, 256, 0, stream>>>(x_ws, ln2 + (size_t)l * H_, hbuf);
        gemmP_kernel<5><<<768, 512, 0, stream>>>(hbuf, wgu_t, act, 4096, 6144, 1024);
        gemmD_kernel<4><<<512, 128, 0, stream>>>(act, wd_t, x_ws, x_ws, 4096, 1024, 3072);
        xin = x_ws;
    }
    rmsnorm_kernel<false><<<T_, 256, 0, stream>>>(x_ws, fnw, out);
}

// Round 20
// 507.344 us; speedup vs baseline: 1.0776x; 1.0776x over previous
//
#include <hip/hip_runtime.h>
#include <hip/hip_bf16.h>

typedef __bf16 bf16;
typedef __bf16 bf16x8 __attribute__((ext_vector_type(8)));
typedef float f32x4 __attribute__((ext_vector_type(4)));

#define DEVINL __device__ __forceinline__

constexpr int L_ = 2, R_ = 4, S_ = 1024, H_ = 1024;
constexpr int NH_ = 16, NKV_ = 8, DH_ = 128;
constexpr int FF_ = 3072;
constexpr int T_ = R_ * S_;  // 4096 tokens

DEVINL void gload16(const bf16* g, bf16* l) {
    __builtin_amdgcn_global_load_lds(
        (const __attribute__((address_space(1))) void*)g,
        (__attribute__((address_space(3))) void*)l, 16, 0, 0);
}

// ---------------------------------------------------------------- RoPE tables
__global__ void rope_tables_kernel(float* __restrict__ cosb, float* __restrict__ sinb) {
    int s = blockIdx.x;
    int i = threadIdx.x;  // 0..63
    float inv = __expf(-(float)i * (1.0f / 64.0f) * 13.815510557964274f);  // 1e6^(-i/64)
    float f = (float)s * inv;
    cosb[s * 64 + i] = cosf(f);
    sinb[s * 64 + i] = sinf(f);
}

// ---------------------------------------------------------------- RMSNorm (f32x4 loads)
template <bool OUT_BF16>
__global__ __launch_bounds__(256) void rmsnorm_kernel(const float* __restrict__ x,
                                                      const float* __restrict__ w,
                                                      void* __restrict__ out) {
    int row = blockIdx.x;
    const float* xr = x + (size_t)row * H_;
    int t = threadIdx.x;
    f32x4 v = *(const f32x4*)(xr + t * 4);
    float ss = v[0] * v[0] + v[1] * v[1] + v[2] * v[2] + v[3] * v[3];
#pragma unroll
    for (int off = 32; off; off >>= 1) ss += __shfl_xor(ss, off);
    __shared__ float part[4];
    if ((t & 63) == 0) part[t >> 6] = ss;
    __syncthreads();
    ss = part[0] + part[1] + part[2] + part[3];
    float r = rsqrtf(ss * (1.0f / (float)H_) + 1e-6f);
    f32x4 wv = *(const f32x4*)(w + t * 4);
#pragma unroll
    for (int j = 0; j < 4; ++j) {
        float o = v[j] * r * wv[j];
        if constexpr (OUT_BF16)
            ((bf16*)out)[(size_t)row * H_ + t * 4 + j] = (bf16)o;
        else
            ((float*)out)[(size_t)row * H_ + t * 4 + j] = o;
    }
}

// ---------------------------------------------------------------- merged weight transpose (all 7 per layer, 1 dispatch)
__global__ __launch_bounds__(256) void transpose_all_kernel(
    const float* __restrict__ Wq, const float* __restrict__ Wk, const float* __restrict__ Wv,
    const float* __restrict__ Wo, const float* __restrict__ Wg, const float* __restrict__ Wu,
    const float* __restrict__ Wd, bf16* __restrict__ wqkv_t, bf16* __restrict__ wo_t,
    bf16* __restrict__ wgu_t, bf16* __restrict__ wd_t) {
    __shared__ float tile[32][33];
    int bid = blockIdx.x;
    const float* in;
    bf16* out;
    int Rk, Cn, mode, tid;
    if (bid < 2048) { in = Wq; out = wqkv_t; Rk = 1024; Cn = 2048; mode = 0; tid = bid; }
    else if (bid < 3072) { in = Wk; out = wqkv_t + (size_t)2048 * 1024; Rk = 1024; Cn = 1024; mode = 0; tid = bid - 2048; }
    else if (bid < 4096) { in = Wv; out = wqkv_t + (size_t)3072 * 1024; Rk = 1024; Cn = 1024; mode = 0; tid = bid - 3072; }
    else if (bid < 6144) { in = Wo; out = wo_t; Rk = 2048; Cn = 1024; mode = 0; tid = bid - 4096; }
    else if (bid < 9216) { in = Wg; out = wgu_t; Rk = 1024; Cn = 3072; mode = 1; tid = bid - 6144; }
    else if (bid < 12288) { in = Wu; out = wgu_t; Rk = 1024; Cn = 3072; mode = 2; tid = bid - 9216; }
    else { in = Wd; out = wd_t; Rk = 3072; Cn = 1024; mode = 0; tid = bid - 12288; }
    int nbx = Cn >> 5;
    int c0 = (tid % nbx) * 32, r0 = (tid / nbx) * 32;
    int t = threadIdx.x;
    int tc = t & 31, tr = t >> 5;
#pragma unroll
    for (int i = 0; i < 4; ++i) {
        int r = tr + i * 8;
        tile[r][tc] = in[(size_t)(r0 + r) * Cn + c0 + tc];
    }
    __syncthreads();
#pragma unroll
    for (int i = 0; i < 4; ++i) {
        int c = c0 + tr + i * 8;
        int n = (mode == 0) ? c : (((c >> 4) << 5) + ((mode == 2) ? 16 : 0) + (c & 15));
        out[(size_t)n * Rk + r0 + tc] = (bf16)tile[tc][tr + i * 8];
    }
}

// ---------------------------------------------------------------- V transpose: qkv[r*S+s][3072+c] -> vt[(r*1024+c)][s]
__global__ __launch_bounds__(256) void vt_kernel(const bf16* __restrict__ qkv,
                                                 bf16* __restrict__ vt) {
    __shared__ bf16 tile[32][34];
    int s0 = blockIdx.x * 32, c0 = blockIdx.y * 32, r = blockIdx.z;
    int t = threadIdx.x, tc = t & 31, tr = t >> 5;
#pragma unroll
    for (int i = 0; i < 4; ++i) {
        int s = tr + i * 8;
        tile[s][tc] = qkv[(size_t)(r * 1024 + s0 + s) * 4096 + 3072 + c0 + tc];
    }
    __syncthreads();
#pragma unroll
    for (int i = 0; i < 4; ++i) {
        int c = tr + i * 8;
        vt[((size_t)(r * 1024 + c0 + c)) * 1024 + s0 + tc] = tile[tc][c];
    }
}

// ---------------------------------------------------------------- gemmT: 256x256 tile, 8 waves (2M x 4N) of 128x64, BK=32
// 3-buffer ring 96KB (1 block/CU), counted vmcnt(4), bn-fastest XCD slice map.
template <int EPI>
__global__ __launch_bounds__(512, 2) void gemmT_kernel(const bf16* __restrict__ A,
                                                       const bf16* __restrict__ Bt,
                                                       void* __restrict__ out,
                                                       int M, int N, int K) {
    __shared__ bf16 lds[49152];  // A: 3 x 8192 elems [0,24576); B: 3 x 8192 [24576,49152)
    const int NT = K >> 5;
    int nbm = M >> 8, nbn = N >> 8;
    int slice = nbn >> 3;
    int id = blockIdx.x;
    int xcd = id & 7, wi = id >> 3;
    int bm = (wi / slice) << 8;
    int bn = (xcd * slice + wi % slice) << 8;
    int t = threadIdx.x, lane = t & 63, w = t >> 6;
    int wm = w >> 2, wn = w & 3;
    int hi = lane >> 4, f = lane & 15;

    int r0 = t >> 2;
    int so = (((t & 3) ^ ((r0 >> 1) & 3)) << 3);
    const bf16* aS0 = A + (size_t)(bm + r0) * K + so;
    const bf16* aS1 = A + (size_t)(bm + 128 + r0) * K + so;
    const bf16* bS0 = Bt + (size_t)(bn + r0) * K + so;
    const bf16* bS1 = Bt + (size_t)(bn + 128 + r0) * K + so;

    f32x4 acc[8][4] = {};

    auto stage = [&](int tt, int sb) {
        gload16(aS0 + tt * 32, lds + sb * 8192 + w * 512);
        gload16(aS1 + tt * 32, lds + sb * 8192 + 4096 + w * 512);
        gload16(bS0 + tt * 32, lds + 24576 + sb * 8192 + w * 512);
        gload16(bS1 + tt * 32, lds + 24576 + sb * 8192 + 4096 + w * 512);
    };

    stage(0, 0);
    stage(1, 1);
    asm volatile("s_waitcnt vmcnt(4)" ::: "memory");
    __builtin_amdgcn_s_barrier();

    int cb = 0;
    for (int tau = 0; tau < NT; ++tau) {
        const bf16* aB = lds + cb * 8192;
        const bf16* bB = lds + 24576 + cb * 8192;
        if (tau + 2 < NT) stage(tau + 2, (cb == 0) ? 2 : cb - 1);
        bf16x8 af[8], bfv[4];
#pragma unroll
        for (int mf = 0; mf < 8; ++mf) {
            int row = wm * 128 + mf * 16 + f;
            af[mf] = *(const bf16x8*)(aB + row * 32 + ((hi ^ ((row >> 1) & 3)) << 3));
        }
#pragma unroll
        for (int nf = 0; nf < 4; ++nf) {
            int row = wn * 64 + nf * 16 + f;
            bfv[nf] = *(const bf16x8*)(bB + row * 32 + ((hi ^ ((row >> 1) & 3)) << 3));
        }
        __builtin_amdgcn_s_setprio(1);
#pragma unroll
        for (int mf = 0; mf < 8; ++mf)
#pragma unroll
            for (int nf = 0; nf < 4; ++nf)
                acc[mf][nf] = __builtin_amdgcn_mfma_f32_16x16x32_bf16(af[mf], bfv[nf],
                                                                      acc[mf][nf], 0, 0, 0);
        __builtin_amdgcn_s_setprio(0);
        if (tau < NT - 2)
            asm volatile("s_waitcnt vmcnt(4)" ::: "memory");
        else
            asm volatile("s_waitcnt vmcnt(0)" ::: "memory");
        __builtin_amdgcn_s_barrier();
        cb = (cb == 2) ? 0 : cb + 1;
    }

    int rb = bm + wm * 128 + hi * 4;
    int cb2 = bn + wn * 64 + f;
#pragma unroll
    for (int mf = 0; mf < 8; ++mf)
#pragma unroll
        for (int nf = 0; nf < 4; ++nf)
#pragma unroll
            for (int g = 0; g < 4; ++g)
                ((bf16*)out)[(size_t)(rb + mf * 16 + g) * N + cb2 + nf * 16] =
                    (bf16)acc[mf][nf][g];
}

// ---------------------------------------------------------------- gemmP: 128x256 tile, wave 64x64, BK=32
// 3-buffer ring 72KB (2 blocks/CU), counted vmcnt(3), bn-fastest XCD slice map.
// EPI: 5 = fused gate-up silu(even16)*odd16 -> bf16 [M][N/2]
template <int EPI>
__global__ __launch_bounds__(512, 4) void gemmP_kernel(const bf16* __restrict__ A,
                                                       const bf16* __restrict__ Bt,
                                                       void* __restrict__ out,
                                                       int M, int N, int K) {
    __shared__ bf16 lds[36864];  // A: 3 x 4096 elems [0,12288); B: 3 x 8192 [12288,36864)
    const int NT = K >> 5;
    int nbm = M >> 7, nbn = N >> 8;
    int slice = nbn >> 3;
    int id = blockIdx.x;
    int xcd = id & 7, wi = id >> 3;
    int bm = (wi / slice) << 7;
    int bn = (xcd * slice + wi % slice) << 8;
    int t = threadIdx.x, lane = t & 63, w = t >> 6;
    int wm = w >> 2, wn = w & 3;
    int hi = lane >> 4, f = lane & 15;

    int srow = t >> 2;
    int ssc = (t & 3) ^ ((srow >> 1) & 3);
    const bf16* aSrc = A + (size_t)(bm + srow) * K + (ssc << 3);
    const bf16* b0Src = Bt + (size_t)(bn + srow) * K + (ssc << 3);
    const bf16* b1Src = Bt + (size_t)(bn + 128 + srow) * K + (ssc << 3);

    f32x4 acc[4][4] = {};

    auto stage = [&](int tt, int sb) {
        gload16(aSrc + tt * 32, lds + sb * 4096 + w * 512);
        gload16(b0Src + tt * 32, lds + 12288 + sb * 8192 + w * 512);
        gload16(b1Src + tt * 32, lds + 12288 + sb * 8192 + 4096 + w * 512);
    };

    stage(0, 0);
    stage(1, 1);
    asm volatile("s_waitcnt vmcnt(3)" ::: "memory");
    __builtin_amdgcn_s_barrier();

    int cb = 0;
    for (int tau = 0; tau < NT; ++tau) {
        const bf16* aB = lds + cb * 4096;
        const bf16* bB = lds + 12288 + cb * 8192;
        if (tau + 2 < NT) stage(tau + 2, (cb == 0) ? 2 : cb - 1);
        bf16x8 af[4], bfv[4];
#pragma unroll
        for (int mf = 0; mf < 4; ++mf) {
            int row = wm * 64 + mf * 16 + f;
            af[mf] = *(const bf16x8*)(aB + row * 32 + ((hi ^ ((row >> 1) & 3)) << 3));
        }
#pragma unroll
        for (int nf = 0; nf < 4; ++nf) {
            int row = wn * 64 + nf * 16 + f;
            bfv[nf] = *(const bf16x8*)(bB + row * 32 + ((hi ^ ((row >> 1) & 3)) << 3));
        }
        __builtin_amdgcn_s_setprio(1);
#pragma unroll
        for (int mf = 0; mf < 4; ++mf)
#pragma unroll
            for (int nf = 0; nf < 4; ++nf)
                acc[mf][nf] = __builtin_amdgcn_mfma_f32_16x16x32_bf16(af[mf], bfv[nf],
                                                                      acc[mf][nf], 0, 0, 0);
        __builtin_amdgcn_s_setprio(0);
        if (tau < NT - 2)
            asm volatile("s_waitcnt vmcnt(3)" ::: "memory");
        else
            asm volatile("s_waitcnt vmcnt(0)" ::: "memory");
        __builtin_amdgcn_s_barrier();
        cb = (cb == 2) ? 0 : cb + 1;
    }

    int rb = bm + wm * 64 + hi * 4;
#pragma unroll
    for (int mf = 0; mf < 4; ++mf) {
        if constexpr (EPI == 5) {
#pragma unroll
            for (int p = 0; p < 2; ++p) {
                int col = ((bn + wn * 64) >> 1) + p * 16 + f;
#pragma unroll
                for (int g = 0; g < 4; ++g) {
                    float gv = acc[mf][2 * p][g], uv = acc[mf][2 * p + 1][g];
                    float sv = gv / (1.0f + __expf(-gv));
                    ((bf16*)out)[(size_t)(rb + mf * 16 + g) * (N / 2) + col] = (bf16)(sv * uv);
                }
            }
        } else {
            int cb2 = bn + wn * 64 + f;
#pragma unroll
            for (int nf = 0; nf < 4; ++nf)
#pragma unroll
                for (int g = 0; g < 4; ++g)
                    ((bf16*)out)[(size_t)(rb + mf * 16 + g) * N + cb2 + nf * 16] =
                        (bf16)acc[mf][nf][g];
        }
    }
}

// ---------------------------------------------------------------- gemmD: skinny-N deep-pipelined GEMM
// 64x128 tile, BK=64, 4 waves (2M x 2N, wave 32x64), 3-buffer ring 72KB (2 blocks/CU).
// counted vmcnt(6). XCD bn-slice map. EPI 4: f32 out = acc + res.
template <int EPI>
__global__ __launch_bounds__(256, 2) void gemmD_kernel(const bf16* __restrict__ A,
                                                       const bf16* __restrict__ Bt,
                                                       void* __restrict__ out,
                                                       const float* __restrict__ res,
                                                       int M, int N, int K) {
    __shared__ bf16 lds[36864];  // A: 3 x 4096 elems [0,12288); B: 3 x 8192 [12288,36864)
    const int NT = K >> 6;
    int nbm = M >> 6;  // BM=64
    int id = blockIdx.x;
    int xcd = id & 7, wi = id >> 3;  // nbn==8: each XCD owns one 128-col stripe
    int bm = (wi % nbm) << 6, bn = xcd << 7;
    int t = threadIdx.x, lane = t & 63, w = t >> 6;
    int wm = w >> 1, wn = w & 1;
    int hi = lane >> 4, f = lane & 15;

    int ar0 = t >> 3, ac0 = t & 7;
    const bf16* aS0 = A + (size_t)(bm + ar0) * K + (((ac0 ^ (ar0 & 7)) & 7) << 3);
    const bf16* aS1 = A + (size_t)(bm + 32 + ar0) * K + (((ac0 ^ ((ar0 + 32) & 7)) & 7) << 3);
    const bf16* bS[4];
#pragma unroll
    for (int j = 0; j < 4; ++j) {
        int row = j * 32 + ar0;
        bS[j] = Bt + (size_t)(bn + row) * K + (((ac0 ^ (row & 7)) & 7) << 3);
    }

    f32x4 acc[2][4] = {};

    auto stage = [&](int tt, int sb) {
        gload16(aS0 + tt * 64, lds + sb * 4096 + w * 512);
        gload16(aS1 + tt * 64, lds + sb * 4096 + 2048 + w * 512);
#pragma unroll
        for (int j = 0; j < 4; ++j)
            gload16(bS[j] + tt * 64, lds + 12288 + sb * 8192 + j * 2048 + w * 512);
    };

    stage(0, 0);
    stage(1, 1);
    asm volatile("s_waitcnt vmcnt(6)" ::: "memory");
    __builtin_amdgcn_s_barrier();

    int cb = 0;
    for (int tau = 0; tau < NT; ++tau) {
        const bf16* aB = lds + cb * 4096;
        const bf16* bB = lds + 12288 + cb * 8192;
        if (tau + 2 < NT) stage(tau + 2, (cb == 0) ? 2 : cb - 1);
        bf16x8 af[2][2], bfv[2][4];
#pragma unroll
        for (int kh = 0; kh < 2; ++kh) {
            int q = kh * 4 + hi;
#pragma unroll
            for (int mf = 0; mf < 2; ++mf) {
                int row = wm * 32 + mf * 16 + f;
                af[kh][mf] = *(const bf16x8*)(aB + row * 64 + ((q ^ (row & 7)) << 3));
            }
#pragma unroll
            for (int nf = 0; nf < 4; ++nf) {
                int row = wn * 64 + nf * 16 + f;
                bfv[kh][nf] = *(const bf16x8*)(bB + row * 64 + ((q ^ (row & 7)) << 3));
            }
        }
        __builtin_amdgcn_s_setprio(1);
#pragma unroll
        for (int kh = 0; kh < 2; ++kh)
#pragma unroll
            for (int mf = 0; mf < 2; ++mf)
#pragma unroll
                for (int nf = 0; nf < 4; ++nf)
                    acc[mf][nf] = __builtin_amdgcn_mfma_f32_16x16x32_bf16(
                        af[kh][mf], bfv[kh][nf], acc[mf][nf], 0, 0, 0);
        __builtin_amdgcn_s_setprio(0);
        if (tau < NT - 2)
            asm volatile("s_waitcnt vmcnt(6)" ::: "memory");
        else
            asm volatile("s_waitcnt vmcnt(0)" ::: "memory");
        __builtin_amdgcn_s_barrier();
        cb = (cb == 2) ? 0 : cb + 1;
    }

    int rb = bm + wm * 32 + hi * 4;
    int cb2 = bn + wn * 64 + f;
#pragma unroll
    for (int mf = 0; mf < 2; ++mf)
#pragma unroll
        for (int nf = 0; nf < 4; ++nf)
#pragma unroll
            for (int g = 0; g < 4; ++g) {
                size_t idx = (size_t)(rb + mf * 16 + g) * N + cb2 + nf * 16;
                ((float*)out)[idx] = acc[mf][nf][g] + res[idx];
            }
}

// ---------------------------------------------------------------- per-head RMS + RoPE for q/k
DEVINL void head_norm_rope(const bf16* __restrict__ src, const float* __restrict__ w,
                           const float* __restrict__ cosb, const float* __restrict__ sinb,
                           int s, int ln, bf16* __restrict__ dst) {
    float x0 = (float)src[ln], x1 = (float)src[ln + 32];
    float x2 = (float)src[ln + 64], x3 = (float)src[ln + 96];
    float ss = x0 * x0 + x1 * x1 + x2 * x2 + x3 * x3;
#pragma unroll
    for (int off = 16; off; off >>= 1) ss += __shfl_xor(ss, off);
    float rr = rsqrtf(ss * (1.0f / 128.0f) + 1e-6f);
    float n0 = x0 * rr * w[ln], n1 = x1 * rr * w[ln + 32];
    float n2 = x2 * rr * w[ln + 64], n3 = x3 * rr * w[ln + 96];
    float c0 = cosb[s * 64 + ln], c1 = cosb[s * 64 + ln + 32];
    float s0 = sinb[s * 64 + ln], s1 = sinb[s * 64 + ln + 32];
    dst[ln] = (bf16)(n0 * c0 - n2 * s0);
    dst[ln + 32] = (bf16)(n1 * c1 - n3 * s1);
    dst[ln + 64] = (bf16)(n2 * c0 + n0 * s0);
    dst[ln + 96] = (bf16)(n3 * c1 + n1 * s1);
}

__global__ __launch_bounds__(256) void qkv_post_kernel(const bf16* __restrict__ qkv,
                                                       const float* __restrict__ qw,
                                                       const float* __restrict__ kw,
                                                       const float* __restrict__ cosb,
                                                       const float* __restrict__ sinb,
                                                       bf16* __restrict__ qo,
                                                       bf16* __restrict__ ko) {
    int tok = blockIdx.x;
    int r = tok >> 10, s = tok & 1023;
    int t = threadIdx.x;
    int g = t >> 5;  // 0..7
    int ln = t & 31;
    const bf16* row = qkv + (size_t)tok * 4096;
#pragma unroll
    for (int hh = 0; hh < 2; ++hh) {
        int h = g + hh * 8;
        head_norm_rope(row + h * 128, qw, cosb, sinb, s, ln,
                       qo + ((size_t)(r * NH_ + h) * S_ + s) * 128);
    }
    head_norm_rope(row + 2048 + g * 128, kw, cosb, sinb, s, ln,
                   ko + ((size_t)(r * NKV_ + g) * S_ + s) * 128);
}

// ---------------------------------------------------------------- flash attention (causal, GQA), NO-MAX softmax
// |q|=|k|=sqrt(128) after unit-weight RMS (RoPE preserves norm) -> |s*scale| <= 11.32, exp safe.
// Row-sum on MFMA pipe via ones operand; zero cross-lane ops; Pl XOR-swizzled.
__global__ __launch_bounds__(256, 2) void flash_kernel(const bf16* __restrict__ q,
                                                       const bf16* __restrict__ k,
                                                       const bf16* __restrict__ vt,
                                                       bf16* __restrict__ out) {
    __shared__ bf16 Kl[64 * 128];    // [kv][d], swizzled
    __shared__ bf16 Vl[128 * 64];    // [d][kv], swizzled
    __shared__ bf16 Pl[4][32 * 64];  // per-wave P, XOR-swizzled
    int bid = blockIdx.x;
    int grp = bid & 63, slot = bid >> 6;
    int strip = (slot < 4) ? (7 - slot) : (slot - 4);  // pair heavy+light per CU
    int h = 2 * (grp & 7) + ((grp >> 3) & 1);
    int r = grp >> 4;
    int kvh = h >> 1;

    int t = threadIdx.x, lane = t & 63, w = t >> 6;
    int arow = lane & 15, hi = lane >> 4;
    int a7 = arow & 7;
    int grow = hi * 4;
    int qbase = strip * 128 + w * 32;

    const bf16* qp = q + ((size_t)(r * NH_ + h) * S_ + qbase) * 128;
    bf16x8 qf[2][4];
#pragma unroll
    for (int m = 0; m < 2; ++m)
#pragma unroll
        for (int kc = 0; kc < 4; ++kc)
            qf[m][kc] = *(const bf16x8*)(qp + (size_t)(m * 16 + arow) * 128 + kc * 32 + hi * 8);

    const bf16* kp = k + (size_t)(r * NKV_ + kvh) * S_ * 128;
    const bf16* vp = vt + (size_t)(r * NKV_ + kvh) * 128 * S_;

    int krow0 = t >> 4, kc16 = t & 15;
    int vrow0 = t >> 3, vc16 = t & 7;

    bf16x8 ones;
#pragma unroll
    for (int i = 0; i < 8; ++i) ones[i] = (bf16)1.0f;

    f32x4 ao[2][8] = {};
    f32x4 aol[2] = {};
    const float scale = 0.08838834764831845f;

    int nt = 2 * (strip + 1);
    bf16x8 krs[4], vrs[4];
#pragma unroll
    for (int i = 0; i < 4; ++i)
        krs[i] = *(const bf16x8*)(kp + (size_t)(krow0 + 16 * i) * 128 + kc16 * 8);
#pragma unroll
    for (int i = 0; i < 4; ++i)
        vrs[i] = *(const bf16x8*)(vp + (size_t)(vrow0 + 32 * i) * S_ + vc16 * 8);

    for (int it = 0; it < nt; ++it) {
        int kv0 = it * 64;
        __syncthreads();
#pragma unroll
        for (int i = 0; i < 4; ++i) {
            int row = krow0 + 16 * i;
            *(bf16x8*)(&Kl[row * 128 + ((kc16 ^ (row & 7)) * 8)]) = krs[i];
        }
#pragma unroll
        for (int i = 0; i < 4; ++i) {
            int row = vrow0 + 32 * i;
            *(bf16x8*)(&Vl[row * 64 + ((vc16 ^ (row & 7)) * 8)]) = vrs[i];
        }
        __syncthreads();
        if (it + 1 < nt) {
            int kvn = kv0 + 64;
#pragma unroll
            for (int i = 0; i < 4; ++i)
                krs[i] = *(const bf16x8*)(kp + (size_t)(kvn + krow0 + 16 * i) * 128 + kc16 * 8);
#pragma unroll
            for (int i = 0; i < 4; ++i)
                vrs[i] = *(const bf16x8*)(vp + (size_t)(vrow0 + 32 * i) * S_ + kvn + vc16 * 8);
        }
        f32x4 sc[2][4];
#pragma unroll
        for (int m = 0; m < 2; ++m)
#pragma unroll
            for (int n = 0; n < 4; ++n) sc[m][n] = (f32x4){0.f, 0.f, 0.f, 0.f};
#pragma unroll
        for (int n = 0; n < 4; ++n) {
            int krw = n * 16 + arow;
#pragma unroll
            for (int kc = 0; kc < 4; ++kc) {
                bf16x8 kf = *(const bf16x8*)(&Kl[krw * 128 + (((kc * 4 + hi) ^ a7) * 8)]);
                sc[0][n] = __builtin_amdgcn_mfma_f32_16x16x32_bf16(qf[0][kc], kf, sc[0][n], 0, 0, 0);
                sc[1][n] = __builtin_amdgcn_mfma_f32_16x16x32_bf16(qf[1][kc], kf, sc[1][n], 0, 0, 0);
            }
        }
#pragma unroll
        for (int m = 0; m < 2; ++m) {
            bool msk = (kv0 + 64 > qbase + m * 16);
#pragma unroll
            for (int n = 0; n < 4; ++n) {
                int chnk = 2 * n + (arow >> 3);
#pragma unroll
                for (int g = 0; g < 4; ++g) {
                    float sval = sc[m][n][g] * scale;
                    if (msk && (kv0 + n * 16 + arow > qbase + m * 16 + grow + g)) sval = -1e30f;
                    float p = __expf(sval);
                    int qr = m * 16 + grow + g;
                    Pl[w][qr * 64 + ((chnk ^ (qr & 7)) * 8) + a7] = (bf16)p;
                }
            }
        }
        bf16x8 pf[2][2];
#pragma unroll
        for (int m = 0; m < 2; ++m) {
            int qr = m * 16 + arow;
#pragma unroll
            for (int ks = 0; ks < 2; ++ks)
                pf[m][ks] = *(const bf16x8*)(&Pl[w][qr * 64 + (((ks * 4 + hi) ^ a7) * 8)]);
        }
#pragma unroll
        for (int m = 0; m < 2; ++m) {
            aol[m] = __builtin_amdgcn_mfma_f32_16x16x32_bf16(pf[m][0], ones, aol[m], 0, 0, 0);
            aol[m] = __builtin_amdgcn_mfma_f32_16x16x32_bf16(pf[m][1], ones, aol[m], 0, 0, 0);
        }
#pragma unroll
        for (int c = 0; c < 8; ++c) {
            int vrw = c * 16 + arow;
#pragma unroll
            for (int ks = 0; ks < 2; ++ks) {
                bf16x8 vf = *(const bf16x8*)(&Vl[vrw * 64 + (((ks * 4 + hi) ^ a7) * 8)]);
                ao[0][c] = __builtin_amdgcn_mfma_f32_16x16x32_bf16(pf[0][ks], vf, ao[0][c], 0, 0, 0);
                ao[1][c] = __builtin_amdgcn_mfma_f32_16x16x32_bf16(pf[1][ks], vf, ao[1][c], 0, 0, 0);
            }
        }
    }
#pragma unroll
    for (int m = 0; m < 2; ++m) {
        f32x4 rl;
#pragma unroll
        for (int g = 0; g < 4; ++g) rl[g] = 1.0f / aol[m][g];
#pragma unroll
        for (int c = 0; c < 8; ++c)
#pragma unroll
            for (int g = 0; g < 4; ++g) {
                int rq = qbase + m * 16 + grow + g;
                out[(size_t)(r * S_ + rq) * 2048 + h * 128 + c * 16 + arow] =
                    (bf16)(ao[m][c][g] * rl[g]);
            }
    }
}

// ---------------------------------------------------------------- host
extern "C" void kernel_launch(void* const* d_in, const int* in_sizes, int n_in,
                              void* d_out, int out_size, void* d_ws, size_t ws_size,
                              hipStream_t stream) {
    const float* hidden = (const float*)d_in[0];
    const float* Wq = (const float*)d_in[1];
    const float* Wk = (const float*)d_in[2];
    const float* Wv = (const float*)d_in[3];
    const float* Wo = (const float*)d_in[4];
    const float* qnw = (const float*)d_in[5];
    const float* knw = (const float*)d_in[6];
    const float* ln1 = (const float*)d_in[7];
    const float* ln2 = (const float*)d_in[8];
    const float* Wg = (const float*)d_in[9];
    const float* Wu = (const float*)d_in[10];
    const float* Wd = (const float*)d_in[11];
    const float* fnw = (const float*)d_in[12];
    float* out = (float*)d_out;

    char* ws = (char*)d_ws;
    size_t off = 0;
    auto alloc = [&](size_t bytes) -> char* {
        char* p = ws + off;
        off += (bytes + 255) & ~(size_t)255;
        return p;
    };
    float* cosb = (float*)alloc((size_t)S_ * 64 * 4);
    float* sinb = (float*)alloc((size_t)S_ * 64 * 4);
    float* x_ws = (float*)alloc((size_t)T_ * H_ * 4);
    bf16* hbuf = (bf16*)alloc((size_t)T_ * H_ * 2);
    bf16* qkv = (bf16*)alloc((size_t)T_ * 4096 * 2);  // shared region: qkv then act
    bf16* act = qkv;
    bf16* qb = (bf16*)alloc((size_t)R_ * NH_ * S_ * 128 * 2);
    bf16* kb = (bf16*)alloc((size_t)R_ * NKV_ * S_ * 128 * 2);
    bf16* vtb = (bf16*)alloc((size_t)R_ * NKV_ * 128 * S_ * 2);
    bf16* attn = (bf16*)alloc((size_t)T_ * 2048 * 2);
    bf16* wqkv_t = (bf16*)alloc((size_t)4096 * 1024 * 2);
    bf16* wo_t = (bf16*)alloc((size_t)1024 * 2048 * 2);
    bf16* wgu_t = (bf16*)alloc((size_t)6144 * 1024 * 2);
    bf16* wd_t = (bf16*)alloc((size_t)1024 * 3072 * 2);

    rope_tables_kernel<<<S_, 64, 0, stream>>>(cosb, sinb);

    const float* xin = hidden;
    for (int l = 0; l < L_; ++l) {
        transpose_all_kernel<<<15360, 256, 0, stream>>>(
            Wq + (size_t)l * H_ * 2048, Wk + (size_t)l * H_ * 1024, Wv + (size_t)l * H_ * 1024,
            Wo + (size_t)l * 2048 * 1024, Wg + (size_t)l * H_ * 3072, Wu + (size_t)l * H_ * 3072,
            Wd + (size_t)l * 3072 * 1024, wqkv_t, wo_t, wgu_t, wd_t);

        // attention block
        rmsnorm_kernel<true><<<T_, 256, 0, stream>>>(xin, ln1 + (size_t)l * H_, hbuf);
        gemmT_kernel<1><<<256, 512, 0, stream>>>(hbuf, wqkv_t, qkv, 4096, 4096, 1024);
        qkv_post_kernel<<<T_, 256, 0, stream>>>(qkv, qnw + (size_t)l * 128, knw + (size_t)l * 128,
                                                cosb, sinb, qb, kb);
        vt_kernel<<<dim3(32, 32, 4), 256, 0, stream>>>(qkv, vtb);
        flash_kernel<<<512, 256, 0, stream>>>(qb, kb, vtb, attn);
        gemmD_kernel<4><<<512, 256, 0, stream>>>(attn, wo_t, x_ws, xin, 4096, 1024, 2048);
        // MLP block
        rmsnorm_kernel<true><<<T_, 256, 0, stream>>>(x_ws, ln2 + (size_t)l * H_, hbuf);
        gemmP_kernel<5><<<768, 512, 0, stream>>>(hbuf, wgu_t, act, 4096, 6144, 1024);
        gemmD_kernel<4><<<512, 256, 0, stream>>>(act, wd_t, x_ws, x_ws, 4096, 1024, 3072);
        xin = x_ws;
    }
    rmsnorm_kernel<false><<<T_, 256, 0, stream>>>(x_ws, fnw, out);
}